// Round 10
// baseline (580.973 us; speedup 1.0000x reference)
//
#include <hip/hip_runtime.h>
#include <hip/hip_fp16.h>
#include <hip/hip_cooperative_groups.h>

namespace cgx = cooperative_groups;

// GraphSAGE 3-layer (mean aggr): N=50000, E=800000, 5->64->64->32.
// Round 10: cooperative mega-kernel, grid sized at runtime from the
// occupancy API (round 9's hard-coded 1024 exceeded the runtime's max and
// the launch failed silently). All phases are grid-stride / grid-robust.
// Full multi-kernel fallback (round-8 pipeline from the same phase bodies)
// if cooperative launch is unsupported or rejected.

#define N_NODES 50000
#define N_EDGES 800000
#define IN_C 5
#define HID_C 64
#define OUT_C 32

#define NB 196        // buckets of 256 nodes (dst >> 8)
#define BCAP 6144     // per-bucket region capacity (mean ~4096, sigma ~64)
#define BWG 256       // bucket chunks
#define BCH (N_EDGES / BWG)  // 3125 edges per chunk

#define NTHR 256

typedef __attribute__((ext_vector_type(8))) short bf16x8;   // 8 bf16 = 4 VGPRs
typedef __attribute__((ext_vector_type(4))) float f32x4;    // 4 fp32 acc

__device__ __forceinline__ int rfl(int v) { return __builtin_amdgcn_readfirstlane(v); }
__device__ __forceinline__ float lanebc(float v, int l) {
    return __int_as_float(__builtin_amdgcn_readlane(__float_as_int(v), l));
}
__device__ __forceinline__ unsigned short f2bf(float f) {  // RNE
    unsigned u = __float_as_uint(f);
    return (unsigned short)((u + 0x7fffu + ((u >> 16) & 1u)) >> 16);
}
__device__ __forceinline__ float bf2f(unsigned short b) {
    return __uint_as_float(((unsigned)b) << 16);
}
__device__ __forceinline__ float2 unpk_h2(unsigned u) {
    __half2 h = *(__half2*)&u;
    return __half22float2(h);
}

// ---------------- LDS shapes ----------------
struct SmBucket {
    int hist[NB], loff[NB], cur[NB], gbase[NB];
    int scanb[256];
    unsigned stage[BCH];
};                       // 16660 B
struct SmSort {
    int sc[256], cnt[256], loff[256], cur[256];
    int stage[BCAP];
};                       // 28672 B
struct SmFused {
    unsigned short Ah[16][136], Al[16][136];
};                       // 8704 B
union SMem {
    SmBucket b;
    SmSort s;
    SmFused f;
};                       // 28672 B

// ---------------- phase bodies (grid-robust) ----------------

__device__ void prep_phase(const float* __restrict__ W2l, const float* __restrict__ W2r,
                           const float* __restrict__ W3l, const float* __restrict__ W3r,
                           unsigned short* __restrict__ W2hi, unsigned short* __restrict__ W2lo,
                           unsigned short* __restrict__ W3hi, unsigned short* __restrict__ W3lo) {
    const int t = blockIdx.x * NTHR + threadIdx.x;
    const int stride = gridDim.x * NTHR;
    for (int p = t; p < 64 * 128; p += stride) {
        int j = p >> 7, k = p & 127;
        float w = (k < 64) ? W2l[j * 64 + k] : W2r[j * 64 + (k - 64)];
        unsigned short h = f2bf(w);
        W2hi[p] = h;
        W2lo[p] = f2bf(w - bf2f(h));
    }
    for (int p = t; p < 32 * 128; p += stride) {
        int j = p >> 7, k = p & 127;
        float w = (k < 64) ? W3l[j * 64 + k] : W3r[j * 64 + (k - 64)];
        unsigned short h = f2bf(w);
        W3hi[p] = h;
        W3lo[p] = f2bf(w - bf2f(h));
    }
}

__device__ void bucket_chunk(SmBucket& sm, int chunk, const int* __restrict__ ei,
                             int* __restrict__ gcur, unsigned* __restrict__ ebuf) {
    const int t = threadIdx.x;
    const int c0 = chunk * BCH;
    if (t < NB) sm.hist[t] = 0;
    __syncthreads();
    for (int i = t; i < BCH; i += 256) {
        int d = ei[N_EDGES + c0 + i];
        atomicAdd(&sm.hist[d >> 8], 1);
    }
    __syncthreads();
    sm.scanb[t] = (t < NB) ? sm.hist[t] : 0;
    __syncthreads();
#pragma unroll
    for (int o = 1; o < 256; o <<= 1) {
        int v = sm.scanb[t];
        int a = (t >= o) ? sm.scanb[t - o] : 0;
        __syncthreads();
        sm.scanb[t] = v + a;
        __syncthreads();
    }
    if (t < NB) {
        int ex = (t == 0) ? 0 : sm.scanb[t - 1];
        sm.loff[t] = ex;
        sm.cur[t] = ex;
        sm.gbase[t] = atomicAdd(&gcur[t], sm.hist[t]);
    }
    __syncthreads();
    for (int i = t; i < BCH; i += 256) {
        int d = ei[N_EDGES + c0 + i];
        int s = ei[c0 + i];
        int b = d >> 8;
        int p = atomicAdd(&sm.cur[b], 1);
        sm.stage[p] = ((unsigned)d << 16) | (unsigned)s;
    }
    __syncthreads();
    for (int i = t; i < BCH; i += 256) {
        unsigned ev = sm.stage[i];
        int b = ev >> 24;
        int pos = sm.gbase[b] + (i - sm.loff[b]);
        if (pos < BCAP) ebuf[b * BCAP + pos] = ev;
    }
    __syncthreads();  // stage reused by next chunk
}

__device__ void bsort_bucket(SmSort& sm, int b, const int* __restrict__ gcur,
                             const unsigned* __restrict__ ebuf, int* __restrict__ row_off,
                             float* __restrict__ inv_deg, int* __restrict__ srcs) {
    const int t = threadIdx.x;
    sm.sc[t] = (t < NB) ? gcur[t] : 0;
    __syncthreads();
#pragma unroll
    for (int o = 1; o < 256; o <<= 1) {
        int v = sm.sc[t];
        int a = (t >= o) ? sm.sc[t - o] : 0;
        __syncthreads();
        sm.sc[t] = v + a;
        __syncthreads();
    }
    const int base = (b == 0) ? 0 : sm.sc[b - 1];
    const int nraw = gcur[b];
    const int n = nraw < BCAP ? nraw : BCAP;
    const int node0 = b << 8;
    const unsigned* eb = ebuf + b * BCAP;

    sm.cnt[t] = 0;
    __syncthreads();
    for (int i = t; i < n; i += 256) atomicAdd(&sm.cnt[(eb[i] >> 16) & 255], 1);
    __syncthreads();
    sm.loff[t] = sm.cnt[t];
    __syncthreads();
#pragma unroll
    for (int o = 1; o < 256; o <<= 1) {
        int v = sm.loff[t];
        int a = (t >= o) ? sm.loff[t - o] : 0;
        __syncthreads();
        sm.loff[t] = v + a;
        __syncthreads();
    }
    int ex = sm.loff[t] - sm.cnt[t];  // exclusive
    sm.cur[t] = ex;
    int node = node0 + t;
    if (node < N_NODES) {
        row_off[node] = base + ex;
        int d = sm.cnt[t];
        inv_deg[node] = 1.0f / (float)(d > 1 ? d : 1);
    }
    if (b == 0 && t == 0) row_off[N_NODES] = N_EDGES;
    __syncthreads();
    for (int i = t; i < n; i += 256) {
        unsigned ev = eb[i];
        int p = atomicAdd(&sm.cur[(ev >> 16) & 255], 1);
        sm.stage[p] = (int)(ev & 0xFFFFu);
    }
    __syncthreads();
    for (int i = t; i < n; i += 256) srcs[base + i] = sm.stage[i];
    __syncthreads();  // sm reused by next bucket
}

__device__ void layer1_phase(const float* __restrict__ x, const int* __restrict__ row_off,
                             const int* __restrict__ srcs, const float* __restrict__ inv_deg,
                             const float* __restrict__ W1l, const float* __restrict__ b1,
                             const float* __restrict__ W1r, __half* __restrict__ h1) {
    const int t = threadIdx.x;
    const int lane = t & 63;
    const int wid = blockIdx.x * 4 + (t >> 6);
    const int nw = gridDim.x * 4;
    const int sub = lane >> 3;  // neighbor slot 0..7
    const int c = lane & 7;     // channel, < IN_C valid

    float wl[IN_C], wr[IN_C];
#pragma unroll
    for (int i = 0; i < IN_C; ++i) {
        wl[i] = W1l[lane * IN_C + i];
        wr[i] = W1r[lane * IN_C + i];
    }
    float bb = b1[lane];

    for (int v = wid; v < N_NODES; v += nw) {
        int beg = rfl(row_off[v]);
        int end = rfl(row_off[v + 1]);
        float sum = 0.f;
        for (int e = beg; e < end; e += 8) {
            int o = e + sub;
            if (o < end && c < IN_C) sum += x[srcs[o] * IN_C + c];
        }
        sum += __shfl_xor(sum, 8, 64);
        sum += __shfl_xor(sum, 16, 64);
        sum += __shfl_xor(sum, 32, 64);
        float summ = sum * inv_deg[v];  // lane i (i<IN_C) holds channel i
        float xv = (lane < IN_C) ? x[v * IN_C + lane] : 0.f;
        float acc = bb;
#pragma unroll
        for (int i = 0; i < IN_C; ++i) {
            acc += wl[i] * lanebc(summ, i);
            acc += wr[i] * lanebc(xv, i);
        }
        h1[v * HID_C + lane] = __float2half(fmaxf(acc, 0.f));
    }
}

template <typename T> __device__ __forceinline__ T cvt_out(float v);
template <> __device__ __forceinline__ float cvt_out<float>(float v) { return v; }
template <> __device__ __forceinline__ __half cvt_out<__half>(float v) { return __float2half(v); }

// Lockstep-4-nodes gather + MFMA (round-8 structure), grid-stride over tiles.
template <int DOUT, bool RELU, typename OutT>
__device__ void fused_phase(SmFused& sm, const __half* __restrict__ h,
                            const int* __restrict__ row_off, const int* __restrict__ srcs,
                            const float* __restrict__ inv_deg,
                            const unsigned short* __restrict__ Whi,
                            const unsigned short* __restrict__ Wlo,
                            const float* __restrict__ bias, OutT* __restrict__ out) {
    const int t = threadIdx.x;
    const int lane = t & 63;
    const int w = t >> 6;
    const int ns = lane >> 4;    // node slot 0..3
    const int cgi = lane & 15;   // channel group (4 halves)
    const unsigned* h32 = (const unsigned*)h;  // row stride 32 uints
    const unsigned* rowb = h32 + cgi * 2;

    for (int tile = blockIdx.x; tile < N_NODES / 16; tile += gridDim.x) {
        const int node0 = tile * 16;
        const int m = w * 4 + ns;
        const int v = node0 + m;
        const int beg = row_off[v];
        const int deg = row_off[v + 1] - beg;

        float f0 = 0.f, f1 = 0.f, f2 = 0.f, f3 = 0.f;
        for (int k = 0; k < deg; k += 4) {
            int i0 = srcs[beg + k];
            int i1 = (k + 1 < deg) ? srcs[beg + k + 1] : i0;
            int i2 = (k + 2 < deg) ? srcs[beg + k + 2] : i0;
            int i3 = (k + 3 < deg) ? srcs[beg + k + 3] : i0;
            uint2 u0 = *(const uint2*)(rowb + i0 * 32);
            uint2 u1 = *(const uint2*)(rowb + i1 * 32);
            uint2 u2 = *(const uint2*)(rowb + i2 * 32);
            uint2 u3 = *(const uint2*)(rowb + i3 * 32);
            float2 a0 = unpk_h2(u0.x), b0 = unpk_h2(u0.y);
            f0 += a0.x; f1 += a0.y; f2 += b0.x; f3 += b0.y;
            if (k + 1 < deg) {
                float2 a = unpk_h2(u1.x), b = unpk_h2(u1.y);
                f0 += a.x; f1 += a.y; f2 += b.x; f3 += b.y;
            }
            if (k + 2 < deg) {
                float2 a = unpk_h2(u2.x), b = unpk_h2(u2.y);
                f0 += a.x; f1 += a.y; f2 += b.x; f3 += b.y;
            }
            if (k + 3 < deg) {
                float2 a = unpk_h2(u3.x), b = unpk_h2(u3.y);
                f0 += a.x; f1 += a.y; f2 += b.x; f3 += b.y;
            }
        }

        uint2 ur = *(const uint2*)(rowb + v * 32);
        float2 r0 = unpk_h2(ur.x), r1 = unpk_h2(ur.y);
        float idg = inv_deg[v];
        float m0 = f0 * idg, m1 = f1 * idg, m2 = f2 * idg, m3 = f3 * idg;

        {   // mean quarter -> LDS (bf16 hi/lo)
            unsigned short a0 = f2bf(m0), a1 = f2bf(m1), a2 = f2bf(m2), a3 = f2bf(m3);
            uint2 hi, lo;
            hi.x = (unsigned)a0 | ((unsigned)a1 << 16);
            hi.y = (unsigned)a2 | ((unsigned)a3 << 16);
            lo.x = (unsigned)f2bf(m0 - bf2f(a0)) | ((unsigned)f2bf(m1 - bf2f(a1)) << 16);
            lo.y = (unsigned)f2bf(m2 - bf2f(a2)) | ((unsigned)f2bf(m3 - bf2f(a3)) << 16);
            *(uint2*)&sm.Ah[m][cgi * 4] = hi;
            *(uint2*)&sm.Al[m][cgi * 4] = lo;
        }
        {   // root quarter -> LDS
            unsigned short a0 = f2bf(r0.x), a1 = f2bf(r0.y), a2 = f2bf(r1.x), a3 = f2bf(r1.y);
            uint2 hi, lo;
            hi.x = (unsigned)a0 | ((unsigned)a1 << 16);
            hi.y = (unsigned)a2 | ((unsigned)a3 << 16);
            lo.x = (unsigned)f2bf(r0.x - bf2f(a0)) | ((unsigned)f2bf(r0.y - bf2f(a1)) << 16);
            lo.y = (unsigned)f2bf(r1.x - bf2f(a2)) | ((unsigned)f2bf(r1.y - bf2f(a3)) << 16);
            *(uint2*)&sm.Ah[m][64 + cgi * 4] = hi;
            *(uint2*)&sm.Al[m][64 + cgi * 4] = lo;
        }
        __syncthreads();

        constexpr int NT = DOUT / 16;
        if (w < NT) {
            const int r = lane & 15;
            const int quad = lane >> 4;
            f32x4 acc = (f32x4){0.f, 0.f, 0.f, 0.f};
#pragma unroll
            for (int ks = 0; ks < 4; ++ks) {
                bf16x8 ah = *(const bf16x8*)&sm.Ah[r][ks * 32 + quad * 8];
                bf16x8 al = *(const bf16x8*)&sm.Al[r][ks * 32 + quad * 8];
                const size_t wb = ((size_t)(w * 16 + r)) * 128 + ks * 32 + quad * 8;
                bf16x8 bh = *(const bf16x8*)(Whi + wb);
                bf16x8 bl = *(const bf16x8*)(Wlo + wb);
                acc = __builtin_amdgcn_mfma_f32_16x16x32_bf16(ah, bh, acc, 0, 0, 0);
                acc = __builtin_amdgcn_mfma_f32_16x16x32_bf16(ah, bl, acc, 0, 0, 0);
                acc = __builtin_amdgcn_mfma_f32_16x16x32_bf16(al, bh, acc, 0, 0, 0);
            }
            float bv = bias[w * 16 + r];
#pragma unroll
            for (int g = 0; g < 4; ++g) {
                int mm = quad * 4 + g;
                float vv = acc[g] + bv;
                if (RELU) vv = fmaxf(vv, 0.f);
                out[(size_t)(node0 + mm) * DOUT + w * 16 + r] = cvt_out<OutT>(vv);
            }
        }
        __syncthreads();  // LDS reused next tile
    }
}

// ---------------- cooperative mega-kernel ----------------

__global__ __launch_bounds__(NTHR, 4) void k_mega(
    const float* x, const int* ei,
    const float* W1l, const float* b1, const float* W1r,
    const float* W2l, const float* b2, const float* W2r,
    const float* W3l, const float* b3, const float* W3r,
    int* gcur, int* rowoff, float* invdeg, int* srcs, unsigned* ebuf,
    __half* h1, __half* h2,
    unsigned short* W2hi, unsigned short* W2lo,
    unsigned short* W3hi, unsigned short* W3lo,
    float* out) {
    __shared__ __align__(16) SMem sm;
    cgx::grid_group grid = cgx::this_grid();

    // P1: weight prep (grid-stride, tiny) + bucket chunks (grid-stride)
    prep_phase(W2l, W2r, W3l, W3r, W2hi, W2lo, W3hi, W3lo);
    for (int c = blockIdx.x; c < BWG; c += gridDim.x)
        bucket_chunk(sm.b, c, ei, gcur, ebuf);
    grid.sync();

    // P2: per-bucket counting sort -> CSR
    for (int b = blockIdx.x; b < NB; b += gridDim.x)
        bsort_bucket(sm.s, b, gcur, ebuf, rowoff, invdeg, srcs);
    grid.sync();

    // P3: layer 1 (5 -> 64), fp16 h1
    layer1_phase(x, rowoff, srcs, invdeg, W1l, b1, W1r, h1);
    grid.sync();

    // P4: fused gather+GEMM layer 2 (64 -> 64, ReLU), h1 -> h2
    fused_phase<HID_C, true, __half>(sm.f, h1, rowoff, srcs, invdeg, W2hi, W2lo, b2, h2);
    grid.sync();

    // P5: fused gather+GEMM layer 3 (64 -> 32), h2 -> out
    fused_phase<OUT_C, false, float>(sm.f, h2, rowoff, srcs, invdeg, W3hi, W3lo, b3, out);
}

// ---------------- fallback wrappers (round-8 pipeline) ----------------

__global__ __launch_bounds__(NTHR) void g_prep(
    const float* W2l, const float* W2r, const float* W3l, const float* W3r,
    unsigned short* W2hi, unsigned short* W2lo,
    unsigned short* W3hi, unsigned short* W3lo) {
    prep_phase(W2l, W2r, W3l, W3r, W2hi, W2lo, W3hi, W3lo);
}

__global__ __launch_bounds__(NTHR) void g_bucket(const int* ei, int* gcur, unsigned* ebuf) {
    __shared__ __align__(16) SmBucket sm;
    bucket_chunk(sm, blockIdx.x, ei, gcur, ebuf);
}

__global__ __launch_bounds__(NTHR) void g_bsort(const int* gcur, const unsigned* ebuf,
                                                int* rowoff, float* invdeg, int* srcs) {
    __shared__ __align__(16) SmSort sm;
    bsort_bucket(sm, blockIdx.x, gcur, ebuf, rowoff, invdeg, srcs);
}

__global__ __launch_bounds__(NTHR) void g_layer1(
    const float* x, const int* rowoff, const int* srcs, const float* invdeg,
    const float* W1l, const float* b1, const float* W1r, __half* h1) {
    layer1_phase(x, rowoff, srcs, invdeg, W1l, b1, W1r, h1);
}

template <int DOUT, bool RELU, typename OutT>
__global__ __launch_bounds__(NTHR) void g_fused(
    const __half* h, const int* rowoff, const int* srcs, const float* invdeg,
    const unsigned short* Whi, const unsigned short* Wlo,
    const float* bias, OutT* out) {
    __shared__ __align__(16) SmFused sm;
    fused_phase<DOUT, RELU, OutT>(sm, h, rowoff, srcs, invdeg, Whi, Wlo, bias, out);
}

// ---------------- launch ----------------

extern "C" void kernel_launch(void* const* d_in, const int* in_sizes, int n_in,
                              void* d_out, int out_size, void* d_ws, size_t ws_size,
                              hipStream_t stream) {
    const float* x   = (const float*)d_in[0];
    const int*   ei  = (const int*)d_in[1];  // [2,E]: row0=src, row1=dst
    const float* W1l = (const float*)d_in[2];
    const float* b1  = (const float*)d_in[3];
    const float* W1r = (const float*)d_in[4];
    const float* W2l = (const float*)d_in[5];
    const float* b2  = (const float*)d_in[6];
    const float* W2r = (const float*)d_in[7];
    const float* W3l = (const float*)d_in[8];
    const float* b3  = (const float*)d_in[9];
    const float* W3r = (const float*)d_in[10];

    char* ws = (char*)d_ws;
    size_t off = 0;
    auto alloc = [&](size_t bytes) -> char* {
        char* p = ws + off;
        off += (bytes + 255) & ~(size_t)255;
        return p;
    };
    int*      gcur   = (int*)alloc(NB * sizeof(int));
    int*      rowoff = (int*)alloc((N_NODES + 1) * sizeof(int));
    float*    invdeg = (float*)alloc(N_NODES * sizeof(float));
    int*      srcs   = (int*)alloc(N_EDGES * sizeof(int));
    unsigned* ebuf   = (unsigned*)alloc((size_t)NB * BCAP * sizeof(unsigned));
    __half*   h1     = (__half*)alloc((size_t)N_NODES * HID_C * sizeof(__half));
    __half*   h2     = (__half*)alloc((size_t)N_NODES * HID_C * sizeof(__half));
    unsigned short* W2hi = (unsigned short*)alloc(64 * 128 * 2);
    unsigned short* W2lo = (unsigned short*)alloc(64 * 128 * 2);
    unsigned short* W3hi = (unsigned short*)alloc(32 * 128 * 2);
    unsigned short* W3lo = (unsigned short*)alloc(32 * 128 * 2);
    float* outp = (float*)d_out;

    hipMemsetAsync(gcur, 0, NB * sizeof(int), stream);

    // Runtime-validated cooperative sizing (round 9's hard-coded 1024 was
    // rejected by the runtime): grid = min(occupancy-derived max, 1024).
    int dev = 0;
    (void)hipGetDevice(&dev);
    int coop = 0, ncu = 0, bpc = 0;
    (void)hipDeviceGetAttribute(&coop, hipDeviceAttributeCooperativeLaunch, dev);
    (void)hipDeviceGetAttribute(&ncu, hipDeviceAttributeMultiprocessorCount, dev);
    hipError_t oe = hipOccupancyMaxActiveBlocksPerMultiprocessor(&bpc, k_mega, NTHR, 0);

    if (coop && oe == hipSuccess && bpc >= 1 && ncu >= 1) {
        int nblk = bpc * ncu;
        if (nblk > 1024) nblk = 1024;
        void* args[] = {
            (void*)&x, (void*)&ei,
            (void*)&W1l, (void*)&b1, (void*)&W1r,
            (void*)&W2l, (void*)&b2, (void*)&W2r,
            (void*)&W3l, (void*)&b3, (void*)&W3r,
            (void*)&gcur, (void*)&rowoff, (void*)&invdeg, (void*)&srcs, (void*)&ebuf,
            (void*)&h1, (void*)&h2,
            (void*)&W2hi, (void*)&W2lo, (void*)&W3hi, (void*)&W3lo,
            (void*)&outp,
        };
        hipError_t le = hipLaunchCooperativeKernel((const void*)k_mega, dim3(nblk),
                                                   dim3(NTHR), args, 0, stream);
        if (le == hipSuccess) return;
    }

    // Fallback: round-8 multi-kernel pipeline (same phase bodies).
    g_prep<<<dim3(48), dim3(NTHR), 0, stream>>>(W2l, W2r, W3l, W3r,
                                                W2hi, W2lo, W3hi, W3lo);
    g_bucket<<<dim3(BWG), dim3(NTHR), 0, stream>>>(ei, gcur, ebuf);
    g_bsort<<<dim3(NB), dim3(NTHR), 0, stream>>>(gcur, ebuf, rowoff, invdeg, srcs);
    g_layer1<<<dim3(N_NODES / 4), dim3(NTHR), 0, stream>>>(
        x, rowoff, srcs, invdeg, W1l, b1, W1r, h1);
    g_fused<HID_C, true, __half><<<dim3(N_NODES / 16), dim3(NTHR), 0, stream>>>(
        h1, rowoff, srcs, invdeg, W2hi, W2lo, b2, h2);
    g_fused<OUT_C, false, float><<<dim3(N_NODES / 16), dim3(NTHR), 0, stream>>>(
        h2, rowoff, srcs, invdeg, W3hi, W3lo, b3, outp);
}

// Round 11
// 172.863 us; speedup vs baseline: 3.3609x; 3.3609x over previous
//
#include <hip/hip_runtime.h>
#include <hip/hip_fp16.h>

// GraphSAGE 3-layer (mean aggr): N=50000, E=800000, 5->64->64->32.
// Round 11: cooperative mega-kernel abandoned (grid.sync + occupancy cost 3x).
// Multi-kernel pipeline (round-8 structure) with k_fused widened to 8 nodes
// per wave / dwordx4 row loads (1KB of scattered rows per wave instruction):
//   k_prep (weights bf16 hi/lo + zero gcur) -> k_bucket -> k_bsort ->
//   k_layer1 -> k_fused<64> -> k_fused<32>.

#define N_NODES 50000
#define N_EDGES 800000
#define IN_C 5
#define HID_C 64
#define OUT_C 32

#define NB 196        // buckets of 256 nodes (dst >> 8)
#define BCAP 6144     // per-bucket region capacity (mean ~4096, sigma ~64)
#define BWG 256       // bucket chunks
#define BCH (N_EDGES / BWG)  // 3125 edges per chunk

typedef __attribute__((ext_vector_type(8))) short bf16x8;   // 8 bf16 = 4 VGPRs
typedef __attribute__((ext_vector_type(4))) float f32x4;    // 4 fp32 acc

__device__ __forceinline__ int rfl(int v) { return __builtin_amdgcn_readfirstlane(v); }
__device__ __forceinline__ float lanebc(float v, int l) {
    return __int_as_float(__builtin_amdgcn_readlane(__float_as_int(v), l));
}
__device__ __forceinline__ unsigned short f2bf(float f) {  // RNE
    unsigned u = __float_as_uint(f);
    return (unsigned short)((u + 0x7fffu + ((u >> 16) & 1u)) >> 16);
}
__device__ __forceinline__ float bf2f(unsigned short b) {
    return __uint_as_float(((unsigned)b) << 16);
}
__device__ __forceinline__ float2 unpk_h2(unsigned u) {
    __half2 h = *(__half2*)&u;
    return __half22float2(h);
}

// ---------------- weight prep: Wcat = [Wl | Wr], bf16 hi/lo; zero gcur -----

__global__ __launch_bounds__(256) void k_prep(
    const float* __restrict__ W2l, const float* __restrict__ W2r,
    const float* __restrict__ W3l, const float* __restrict__ W3r,
    unsigned short* __restrict__ W2hi, unsigned short* __restrict__ W2lo,
    unsigned short* __restrict__ W3hi, unsigned short* __restrict__ W3lo,
    int* __restrict__ gcur) {
    if (blockIdx.x == 0 && threadIdx.x < NB) gcur[threadIdx.x] = 0;
    const int t = blockIdx.x * 256 + threadIdx.x;
    const int stride = gridDim.x * 256;
    for (int p = t; p < 64 * 128; p += stride) {
        int j = p >> 7, k = p & 127;
        float w = (k < 64) ? W2l[j * 64 + k] : W2r[j * 64 + (k - 64)];
        unsigned short h = f2bf(w);
        W2hi[p] = h;
        W2lo[p] = f2bf(w - bf2f(h));
    }
    for (int p = t; p < 32 * 128; p += stride) {
        int j = p >> 7, k = p & 127;
        float w = (k < 64) ? W3l[j * 64 + k] : W3r[j * 64 + (k - 64)];
        unsigned short h = f2bf(w);
        W3hi[p] = h;
        W3lo[p] = f2bf(w - bf2f(h));
    }
}

// ---------------- CSR build: bucketed counting sort ----------------

__global__ __launch_bounds__(256) void k_bucket(const int* __restrict__ ei,
                                                int* __restrict__ gcur,
                                                unsigned* __restrict__ ebuf) {
    __shared__ int hist[NB];
    __shared__ int loff[NB];
    __shared__ int cur[NB];
    __shared__ int gbase[NB];
    __shared__ int scanb[256];
    __shared__ unsigned stage[BCH];
    const int t = threadIdx.x;
    const int c0 = blockIdx.x * BCH;

    if (t < NB) hist[t] = 0;
    __syncthreads();
    for (int i = t; i < BCH; i += 256) {
        int d = ei[N_EDGES + c0 + i];
        atomicAdd(&hist[d >> 8], 1);
    }
    __syncthreads();
    scanb[t] = (t < NB) ? hist[t] : 0;
    __syncthreads();
#pragma unroll
    for (int o = 1; o < 256; o <<= 1) {
        int v = scanb[t];
        int a = (t >= o) ? scanb[t - o] : 0;
        __syncthreads();
        scanb[t] = v + a;
        __syncthreads();
    }
    if (t < NB) {
        int ex = (t == 0) ? 0 : scanb[t - 1];
        loff[t] = ex;
        cur[t] = ex;
        gbase[t] = atomicAdd(&gcur[t], hist[t]);
    }
    __syncthreads();
    for (int i = t; i < BCH; i += 256) {
        int d = ei[N_EDGES + c0 + i];
        int s = ei[c0 + i];
        int b = d >> 8;
        int p = atomicAdd(&cur[b], 1);
        stage[p] = ((unsigned)d << 16) | (unsigned)s;
    }
    __syncthreads();
    for (int i = t; i < BCH; i += 256) {
        unsigned ev = stage[i];
        int b = ev >> 24;
        int pos = gbase[b] + (i - loff[b]);
        if (pos < BCAP) ebuf[b * BCAP + pos] = ev;
    }
}

__global__ __launch_bounds__(256) void k_bsort(const int* __restrict__ gcur,
                                               const unsigned* __restrict__ ebuf,
                                               int* __restrict__ row_off,
                                               float* __restrict__ inv_deg,
                                               int* __restrict__ srcs) {
    __shared__ int sc[256];
    __shared__ int cnt[256];
    __shared__ int loff[256];
    __shared__ int cur[256];
    __shared__ int stage[BCAP];
    const int t = threadIdx.x;
    const int b = blockIdx.x;

    sc[t] = (t < NB) ? gcur[t] : 0;
    __syncthreads();
#pragma unroll
    for (int o = 1; o < 256; o <<= 1) {
        int v = sc[t];
        int a = (t >= o) ? sc[t - o] : 0;
        __syncthreads();
        sc[t] = v + a;
        __syncthreads();
    }
    const int base = (b == 0) ? 0 : sc[b - 1];
    const int nraw = gcur[b];
    const int n = nraw < BCAP ? nraw : BCAP;
    const int node0 = b << 8;
    const unsigned* eb = ebuf + b * BCAP;

    cnt[t] = 0;
    __syncthreads();
    for (int i = t; i < n; i += 256) atomicAdd(&cnt[(eb[i] >> 16) & 255], 1);
    __syncthreads();
    loff[t] = cnt[t];
    __syncthreads();
#pragma unroll
    for (int o = 1; o < 256; o <<= 1) {
        int v = loff[t];
        int a = (t >= o) ? loff[t - o] : 0;
        __syncthreads();
        loff[t] = v + a;
        __syncthreads();
    }
    int ex = loff[t] - cnt[t];  // exclusive
    cur[t] = ex;
    int node = node0 + t;
    if (node < N_NODES) {
        row_off[node] = base + ex;
        int d = cnt[t];
        inv_deg[node] = 1.0f / (float)(d > 1 ? d : 1);
    }
    if (b == 0 && t == 0) row_off[N_NODES] = N_EDGES;
    __syncthreads();
    for (int i = t; i < n; i += 256) {
        unsigned ev = eb[i];
        int p = atomicAdd(&cur[(ev >> 16) & 255], 1);
        stage[p] = (int)(ev & 0xFFFFu);
    }
    __syncthreads();
    for (int i = t; i < n; i += 256) srcs[base + i] = stage[i];
}

// ---------------- Layer 1: 5 -> 64 fused matvec, ReLU, fp16 output ---------

__global__ __launch_bounds__(256) void k_layer1(
    const float* __restrict__ x, const int* __restrict__ row_off,
    const int* __restrict__ srcs, const float* __restrict__ inv_deg,
    const float* __restrict__ W1l, const float* __restrict__ b1,
    const float* __restrict__ W1r, __half* __restrict__ h1) {
    const int t = threadIdx.x;
    const int lane = t & 63;
    const int v = blockIdx.x * 4 + (t >> 6);
    if (v >= N_NODES) return;
    const int sub = lane >> 3;  // neighbor slot 0..7
    const int c = lane & 7;     // channel, < IN_C valid

    float wl[IN_C], wr[IN_C];
#pragma unroll
    for (int i = 0; i < IN_C; ++i) {
        wl[i] = W1l[lane * IN_C + i];
        wr[i] = W1r[lane * IN_C + i];
    }
    float bb = b1[lane];

    int beg = rfl(row_off[v]);
    int end = rfl(row_off[v + 1]);
    float sum = 0.f;
    for (int e = beg; e < end; e += 8) {
        int o = e + sub;
        if (o < end && c < IN_C) sum += x[srcs[o] * IN_C + c];
    }
    sum += __shfl_xor(sum, 8, 64);
    sum += __shfl_xor(sum, 16, 64);
    sum += __shfl_xor(sum, 32, 64);
    float summ = sum * inv_deg[v];  // lane i (i<IN_C) holds channel i
    float xv = (lane < IN_C) ? x[v * IN_C + lane] : 0.f;
    float acc = bb;
#pragma unroll
    for (int i = 0; i < IN_C; ++i) {
        acc += wl[i] * lanebc(summ, i);
        acc += wr[i] * lanebc(xv, i);
    }
    h1[v * HID_C + lane] = __float2half(fmaxf(acc, 0.f));
}

// ---------------- fused gather + GEMM (layers 2/3) ----------------
// Block = 4 waves = 32-node tile. Gather: lane -> (node slot ns=l>>3,
// channel group cg=l&7); each lane loads one uint4 (16B, 8 fp16 channels)
// per neighbor of its node -> one wave instruction fetches 8 scattered 128B
// rows (1KB). No cross-lane reduction. k-loop unrolled x4 (4 srcs + 4
// dwordx4 in flight). Each lane writes its node's mean+root 8-channel
// chunks (bf16 hi/lo) to the 32-row LDS A tile (stride 152: bank-balanced).
// One barrier; waves cover 2 row-halves x DOUT/16 col-tiles of MFMAs.

template <typename T> __device__ __forceinline__ T cvt_out(float v);
template <> __device__ __forceinline__ float cvt_out<float>(float v) { return v; }
template <> __device__ __forceinline__ __half cvt_out<__half>(float v) { return __float2half(v); }

template <int DOUT, bool RELU, typename OutT>
__global__ __launch_bounds__(256) void k_fused(
    const __half* __restrict__ h, const int* __restrict__ row_off,
    const int* __restrict__ srcs, const float* __restrict__ inv_deg,
    const unsigned short* __restrict__ Whi, const unsigned short* __restrict__ Wlo,
    const float* __restrict__ bias, OutT* __restrict__ out) {
    constexpr int AP = 152;  // ushorts/row; stride 76 words = 12 mod 32 banks
    __shared__ __align__(16) unsigned short Ah[32][AP];
    __shared__ __align__(16) unsigned short Al[32][AP];
    const int t = threadIdx.x;
    const int lane = t & 63;
    const int w = t >> 6;
    const int ns = lane >> 3;   // node slot 0..7
    const int cg = lane & 7;    // channel group (8 halves = 16B)
    const int node0 = blockIdx.x * 32;
    const int m = w * 8 + ns;   // block-local node 0..31
    const int v = node0 + m;
    const bool valid = v < N_NODES;
    const uint4* h4 = (const uint4*)h;  // row = 8 uint4

    int beg = 0, deg = 0;
    if (valid) {
        beg = row_off[v];
        deg = row_off[v + 1] - beg;
    }

    float s0 = 0.f, s1 = 0.f, s2 = 0.f, s3 = 0.f;
    float s4 = 0.f, s5 = 0.f, s6 = 0.f, s7 = 0.f;
    for (int k = 0; k < deg; k += 4) {
        int i0 = srcs[beg + k];
        int i1 = (k + 1 < deg) ? srcs[beg + k + 1] : i0;
        int i2 = (k + 2 < deg) ? srcs[beg + k + 2] : i0;
        int i3 = (k + 3 < deg) ? srcs[beg + k + 3] : i0;
        uint4 u0 = h4[i0 * 8 + cg];
        uint4 u1 = h4[i1 * 8 + cg];
        uint4 u2 = h4[i2 * 8 + cg];
        uint4 u3 = h4[i3 * 8 + cg];
        {
            float2 a = unpk_h2(u0.x), b = unpk_h2(u0.y);
            float2 c = unpk_h2(u0.z), d = unpk_h2(u0.w);
            s0 += a.x; s1 += a.y; s2 += b.x; s3 += b.y;
            s4 += c.x; s5 += c.y; s6 += d.x; s7 += d.y;
        }
        if (k + 1 < deg) {
            float2 a = unpk_h2(u1.x), b = unpk_h2(u1.y);
            float2 c = unpk_h2(u1.z), d = unpk_h2(u1.w);
            s0 += a.x; s1 += a.y; s2 += b.x; s3 += b.y;
            s4 += c.x; s5 += c.y; s6 += d.x; s7 += d.y;
        }
        if (k + 2 < deg) {
            float2 a = unpk_h2(u2.x), b = unpk_h2(u2.y);
            float2 c = unpk_h2(u2.z), d = unpk_h2(u2.w);
            s0 += a.x; s1 += a.y; s2 += b.x; s3 += b.y;
            s4 += c.x; s5 += c.y; s6 += d.x; s7 += d.y;
        }
        if (k + 3 < deg) {
            float2 a = unpk_h2(u3.x), b = unpk_h2(u3.y);
            float2 c = unpk_h2(u3.z), d = unpk_h2(u3.w);
            s0 += a.x; s1 += a.y; s2 += b.x; s3 += b.y;
            s4 += c.x; s5 += c.y; s6 += d.x; s7 += d.y;
        }
    }

    uint4 ur = make_uint4(0u, 0u, 0u, 0u);
    float idg = 0.f;
    if (valid) {
        ur = h4[v * 8 + cg];
        idg = inv_deg[v];
    }
    float m0 = s0 * idg, m1 = s1 * idg, m2 = s2 * idg, m3 = s3 * idg;
    float m4 = s4 * idg, m5 = s5 * idg, m6 = s6 * idg, m7 = s7 * idg;

    {   // mean 8-channel chunk -> LDS (bf16 hi/lo)
        unsigned short a0 = f2bf(m0), a1 = f2bf(m1), a2 = f2bf(m2), a3 = f2bf(m3);
        unsigned short a4 = f2bf(m4), a5 = f2bf(m5), a6 = f2bf(m6), a7 = f2bf(m7);
        uint4 hi, lo;
        hi.x = (unsigned)a0 | ((unsigned)a1 << 16);
        hi.y = (unsigned)a2 | ((unsigned)a3 << 16);
        hi.z = (unsigned)a4 | ((unsigned)a5 << 16);
        hi.w = (unsigned)a6 | ((unsigned)a7 << 16);
        lo.x = (unsigned)f2bf(m0 - bf2f(a0)) | ((unsigned)f2bf(m1 - bf2f(a1)) << 16);
        lo.y = (unsigned)f2bf(m2 - bf2f(a2)) | ((unsigned)f2bf(m3 - bf2f(a3)) << 16);
        lo.z = (unsigned)f2bf(m4 - bf2f(a4)) | ((unsigned)f2bf(m5 - bf2f(a5)) << 16);
        lo.w = (unsigned)f2bf(m6 - bf2f(a6)) | ((unsigned)f2bf(m7 - bf2f(a7)) << 16);
        *(uint4*)&Ah[m][cg * 8] = hi;
        *(uint4*)&Al[m][cg * 8] = lo;
    }
    {   // root 8-channel chunk -> LDS
        float2 p0 = unpk_h2(ur.x), p1 = unpk_h2(ur.y);
        float2 p2 = unpk_h2(ur.z), p3 = unpk_h2(ur.w);
        unsigned short a0 = f2bf(p0.x), a1 = f2bf(p0.y), a2 = f2bf(p1.x), a3 = f2bf(p1.y);
        unsigned short a4 = f2bf(p2.x), a5 = f2bf(p2.y), a6 = f2bf(p3.x), a7 = f2bf(p3.y);
        uint4 hi, lo;
        hi.x = (unsigned)a0 | ((unsigned)a1 << 16);
        hi.y = (unsigned)a2 | ((unsigned)a3 << 16);
        hi.z = (unsigned)a4 | ((unsigned)a5 << 16);
        hi.w = (unsigned)a6 | ((unsigned)a7 << 16);
        lo.x = (unsigned)f2bf(p0.x - bf2f(a0)) | ((unsigned)f2bf(p0.y - bf2f(a1)) << 16);
        lo.y = (unsigned)f2bf(p1.x - bf2f(a2)) | ((unsigned)f2bf(p1.y - bf2f(a3)) << 16);
        lo.z = (unsigned)f2bf(p2.x - bf2f(a4)) | ((unsigned)f2bf(p2.y - bf2f(a5)) << 16);
        lo.w = (unsigned)f2bf(p3.x - bf2f(a6)) | ((unsigned)f2bf(p3.y - bf2f(a7)) << 16);
        *(uint4*)&Ah[m][64 + cg * 8] = hi;
        *(uint4*)&Al[m][64 + cg * 8] = lo;
    }
    __syncthreads();

    constexpr int CT = DOUT / 16;       // col tiles (4 or 2)
    constexpr int NTILES = 2 * CT;      // x 2 row-halves (8 or 4)
    const int r = lane & 15;
    const int quad = lane >> 4;
#pragma unroll
    for (int ti = w; ti < NTILES; ti += 4) {
        const int n = ti % CT;
        const int rh = ti / CT;
        f32x4 acc = (f32x4){0.f, 0.f, 0.f, 0.f};
#pragma unroll
        for (int ks = 0; ks < 4; ++ks) {
            bf16x8 ah = *(const bf16x8*)&Ah[rh * 16 + r][ks * 32 + quad * 8];
            bf16x8 al = *(const bf16x8*)&Al[rh * 16 + r][ks * 32 + quad * 8];
            const size_t wb = ((size_t)(n * 16 + r)) * 128 + ks * 32 + quad * 8;
            bf16x8 bh = *(const bf16x8*)(Whi + wb);
            bf16x8 bl = *(const bf16x8*)(Wlo + wb);
            acc = __builtin_amdgcn_mfma_f32_16x16x32_bf16(ah, bh, acc, 0, 0, 0);
            acc = __builtin_amdgcn_mfma_f32_16x16x32_bf16(ah, bl, acc, 0, 0, 0);
            acc = __builtin_amdgcn_mfma_f32_16x16x32_bf16(al, bh, acc, 0, 0, 0);
        }
        float bv = bias[n * 16 + r];
#pragma unroll
        for (int g = 0; g < 4; ++g) {
            int node = node0 + rh * 16 + quad * 4 + g;
            if (node < N_NODES) {
                float vv = acc[g] + bv;
                if (RELU) vv = fmaxf(vv, 0.f);
                out[(size_t)node * DOUT + n * 16 + r] = cvt_out<OutT>(vv);
            }
        }
    }
}

// ---------------- launch ----------------

extern "C" void kernel_launch(void* const* d_in, const int* in_sizes, int n_in,
                              void* d_out, int out_size, void* d_ws, size_t ws_size,
                              hipStream_t stream) {
    const float* x   = (const float*)d_in[0];
    const int*   ei  = (const int*)d_in[1];  // [2,E]: row0=src, row1=dst
    const float* W1l = (const float*)d_in[2];
    const float* b1  = (const float*)d_in[3];
    const float* W1r = (const float*)d_in[4];
    const float* W2l = (const float*)d_in[5];
    const float* b2  = (const float*)d_in[6];
    const float* W2r = (const float*)d_in[7];
    const float* W3l = (const float*)d_in[8];
    const float* b3  = (const float*)d_in[9];
    const float* W3r = (const float*)d_in[10];

    char* ws = (char*)d_ws;
    size_t off = 0;
    auto alloc = [&](size_t bytes) -> char* {
        char* p = ws + off;
        off += (bytes + 255) & ~(size_t)255;
        return p;
    };
    int*      gcur   = (int*)alloc(NB * sizeof(int));
    int*      rowoff = (int*)alloc((N_NODES + 1) * sizeof(int));
    float*    invdeg = (float*)alloc(N_NODES * sizeof(float));
    int*      srcs   = (int*)alloc(N_EDGES * sizeof(int));
    unsigned* ebuf   = (unsigned*)alloc((size_t)NB * BCAP * sizeof(unsigned));
    __half*   h1     = (__half*)alloc((size_t)N_NODES * HID_C * sizeof(__half));
    __half*   h2     = (__half*)alloc((size_t)N_NODES * HID_C * sizeof(__half));
    unsigned short* W2hi = (unsigned short*)alloc(64 * 128 * 2);
    unsigned short* W2lo = (unsigned short*)alloc(64 * 128 * 2);
    unsigned short* W3hi = (unsigned short*)alloc(32 * 128 * 2);
    unsigned short* W3lo = (unsigned short*)alloc(32 * 128 * 2);

    // CSR build (k_prep zeroes gcur; same-stream ordering)
    k_prep<<<dim3(48), dim3(256), 0, stream>>>(W2l, W2r, W3l, W3r,
                                               W2hi, W2lo, W3hi, W3lo, gcur);
    k_bucket<<<dim3(BWG), dim3(256), 0, stream>>>(ei, gcur, ebuf);
    k_bsort<<<dim3(NB), dim3(256), 0, stream>>>(gcur, ebuf, rowoff, invdeg, srcs);

    // layer 1 (fused matvec): x -> h1 (fp16)
    k_layer1<<<dim3(N_NODES / 4), dim3(256), 0, stream>>>(
        x, rowoff, srcs, invdeg, W1l, b1, W1r, h1);

    // layer 2: fused gather+gemm, h1 -> h2 (fp16, ReLU)
    const int FT = (N_NODES + 31) / 32;  // 1563 tiles
    k_fused<HID_C, true, __half><<<dim3(FT), dim3(256), 0, stream>>>(
        h1, rowoff, srcs, invdeg, W2hi, W2lo, b2, h2);

    // layer 3: fused gather+gemm, h2 -> out (fp32)
    k_fused<OUT_C, false, float><<<dim3(FT), dim3(256), 0, stream>>>(
        h2, rowoff, srcs, invdeg, W3hi, W3lo, b3, (float*)d_out);
}